// Round 3
// baseline (337.571 us; speedup 1.0000x reference)
//
#include <hip/hip_runtime.h>

// CTC forward loss (sum, zero_infinity), B=32, T=1024, V=1024, L=256, S=513.
//
// Pass 1 (ctc_gather): per (b,t) row — coalesced row copy into LDS via
//   global_load_lds (4x 1KB per wave), then the 257 needed probs gathered
//   from LDS. R11: compacted output goes to WORKSPACE (stride 256) when
//   ws_size permits -> lp is read-only (no in-place mutation, no restore
//   dependency). Guarded fallback: in-place (stride 1024), as R10.
//
// Pass 2 (ctc_dp): R11 — producer/consumer handshake DELETED. R10 post-
//   mortem: __hip_atomic_store(RELEASE, WORKGROUP) emits s_waitcnt
//   vmcnt(0) before the Pf store, draining the just-issued prefetch ->
//   pipeline depth 0, consumer stalled ~215 cyc/step at chunk boundaries
//   (R9 and R10 both ~250 cyc/step despite different LDS scheduling).
//   Now: ONE wave per batch item register-stages chunks straight from
//   global (16x global_load_dwordx4 -> float4 qa[16]/qbf[16] double
//   buffer). No LDS ring, no atomics, no vmcnt(0) in the loop — the
//   compiler emits counted vmcnt on first register use, and loads are
//   issued a full chunk (~700 cyc of VALU) before use. Blanks staged to
//   LDS once at prologue; per-chunk uniform ds_read_b128, prefetched one
//   chunk ahead. Numerics bit-identical to R9/R10 (pass, absmax 1024).
//
// (R12 = R11 resubmitted verbatim: the R11 bench died on GPU acquisition
//  timeout before running — no measurement was taken.)

constexpr int B_ = 32, T_ = 1024, V_ = 1024, L_ = 256;
constexpr int CH = 16;           // steps per chunk
constexpr int NCHUNK = 64;       // 64*16 covers t = 1..1024 (t>=tend guarded)
constexpr float LN2F = 0.6931471805599453f;

typedef const __attribute__((address_space(1))) unsigned int* gp_t;
typedef __attribute__((address_space(3))) unsigned int* lp_t;

template <int CTRL>
__device__ __forceinline__ float dpp_fmax(float x) {
    // old=0, row_mask=bank_mask=0xf, bound_ctrl=1 (invalid src -> 0);
    // states are nonnegative so fmax with 0 is identity.
    const int t = __builtin_amdgcn_update_dpp(0, __float_as_int(x), CTRL, 0xf, 0xf, true);
    return fmaxf(x, __int_as_float(t));
}

__device__ __forceinline__ float wave_max_dpp(float x) {
    x = dpp_fmax<0x111>(x);   // row_shr:1
    x = dpp_fmax<0x112>(x);   // row_shr:2
    x = dpp_fmax<0x114>(x);   // row_shr:4
    x = dpp_fmax<0x118>(x);   // row_shr:8   (lane 15,31,47,63 = row max)
    x = dpp_fmax<0x142>(x);   // row_bcast:15
    x = dpp_fmax<0x143>(x);   // row_bcast:31 (lane 63 = wave max)
    return __int_as_float(__builtin_amdgcn_readlane(__float_as_int(x), 63));
}

__device__ __forceinline__ float dpp_wave_shr1(float x) {
    // lane i <- lane i-1 across the whole wave; lane 0 -> 0 (bound_ctrl)
    return __int_as_float(
        __builtin_amdgcn_update_dpp(0, __float_as_int(x), 0x138, 0xf, 0xf, true));
}

__global__ __launch_bounds__(256, 8) void ctc_gather(
    const float* __restrict__ lp, float* __restrict__ qdst, int qstride,
    const int* __restrict__ labels, float* __restrict__ blanks)
{
    __shared__ float srow[4][V_];              // 16 KB: one row per wave
    const int wave = threadIdx.x >> 6;
    const int lane = threadIdx.x & 63;
    const int r = blockIdx.x * 4 + wave;       // row in [0, B*T)
    const int b = r >> 10;                     // T = 1024
    const float* row = lp + (size_t)r * V_;
    float* orow = qdst + (size_t)r * qstride;
    const int* labb = labels + b * L_;

    // coalesced row -> LDS (1 KB per instruction); wave-private region,
    // so no barrier is needed anywhere in this kernel.
    #pragma unroll
    for (int j = 0; j < 4; ++j)
        __builtin_amdgcn_global_load_lds((gp_t)(row + 256 * j + 4 * lane),
                                         (lp_t)&srow[wave][256 * j], 16, 0, 0);
    const int4 e = *(const int4*)(labb + 4 * lane);
    asm volatile("s_waitcnt vmcnt(0)" ::: "memory");  // row fully in LDS
                                                      // (also WAR-safe for
                                                      // the in-place path)
    __builtin_amdgcn_sched_barrier(0);
    const float v0 = srow[wave][e.x];
    const float v1 = srow[wave][e.y];
    const float v2 = srow[wave][e.z];
    const float v3 = srow[wave][e.w];
    const float vb = srow[wave][0];
    float4 q;
    q.x = __expf(v0); q.y = __expf(v1); q.z = __expf(v2); q.w = __expf(v3);
    const float qb = __expf(vb);
    *(float4*)(orow + 4 * lane) = q;           // cols 4l..4l+3 (compact)
    if (lane == 0) {
        const int t = r & (T_ - 1);
        blanks[(r & ~(T_ - 1)) + ((t + T_ - 1) & (T_ - 1))] = qb;  // shifted
    }
}

__global__ __launch_bounds__(64, 1) void ctc_dp(
    const float* __restrict__ Q, int qstride,
    const float* __restrict__ blanks, const int* __restrict__ labels,
    const int* __restrict__ input_lens, const int* __restrict__ label_lens,
    float* __restrict__ out)
{
    __shared__ float blk[T_];                  // shifted blank probs (4 KB)
    const int b    = blockIdx.x;
    const int lane = threadIdx.x & 63;
    const float* Qb  = Q + (size_t)b * T_ * qstride;
    const float* blg = blanks + b * T_;
    const int*  labb = labels + b * L_;
    const int il = input_lens[b];
    const int ll = label_lens[b];
    const int tend = il < T_ ? il : T_;

    // blanks -> LDS, once (single wave: no barrier needed, just vmcnt)
    #pragma unroll
    for (int i = 0; i < 4; ++i)
        __builtin_amdgcn_global_load_lds((gp_t)(blg + 256 * i + 4 * lane),
                                         (lp_t)&blk[256 * i], 16, 0, 0);

    const int4 e  = *(const int4*)(labb + 4 * lane);
    const int  ep = (lane > 0) ? labb[4 * lane - 1] : -1;
    const float kf0 = ((8 * lane + 1) >= 3 && e.x != ep) ? 1.f : 0.f;
    const float kf1 = (e.y != e.x) ? 1.f : 0.f;
    const float kf2 = (e.z != e.y) ? 1.f : 0.f;
    const float kf3 = (e.w != e.z) ? 1.f : 0.f;
    const float bl0 = blg[T_ - 1];             // blank(t=0), shifted slot
    const float q00 = Qb[0];                   // label-state-1 prob at t=0
    float p0 = (lane == 0) ? bl0 : 0.f;
    float p1 = (lane == 0) ? q00 : 0.f;
    float p2 = 0.f, p3 = 0.f, p4 = 0.f, p5 = 0.f,
          p6 = 0.f, p7 = 0.f, p8 = 0.f;
    int Esc = 0;        // true alpha = stored * 2^{-Esc}
    float pm1 = 0.f;    // alpha[8l-1] entering next step
    float sfP = 1.f, sfM = 1.f;                // pending deferred scales

    asm volatile("s_waitcnt vmcnt(0)" ::: "memory");   // blanks in LDS
    __builtin_amdgcn_sched_barrier(0);

    // Wave-max via DPP (VALU pipe), exact pow2 factor -> max ~= 2^64.
    auto snap = [&]() -> float {
        float m = fmaxf(fmaxf(fmaxf(fmaxf(p0, p1), fmaxf(p2, p3)),
                              fmaxf(fmaxf(p4, p5), fmaxf(p6, p7))), p8);
        m = wave_max_dpp(m);
        const unsigned eb = (__float_as_uint(m) >> 23) & 0xffu;
        if (eb >= 1u && eb <= 254u) {
            unsigned k = 318u - eb;            // biased exp of 2^(64-(eb-127))
            if (k > 254u) k = 254u;            // clamp (max sf = 2^127)
            Esc += (int)k - 127;
            return __uint_as_float(k << 23);   // exact 2^(k-127)
        }
        return 1.f;
    };

    auto qaddr = [&](int t) -> const float4* {
        return (const float4*)(Qb + (size_t)t * qstride + 4 * lane);
    };

    // register double buffer: 16 rows/chunk, issued one chunk ahead
    float4 qa[CH], qbf[CH];
    float4 bbA[4], bbB[4];
    #pragma unroll
    for (int i = 0; i < CH; ++i) { int t = 1 + i; qa[i] = *qaddr(t); }
    #pragma unroll
    for (int i = 0; i < CH; ++i) {
        int t = 1 + CH + i; if (t > T_ - 1) t = T_ - 1;
        qbf[i] = *qaddr(t);
    }
    #pragma unroll
    for (int j = 0; j < 4; ++j) bbA[j] = *(const float4*)&blk[4 * j];
    #pragma unroll
    for (int j = 0; j < 4; ++j) bbB[j] = *(const float4*)&blk[CH + 4 * j];

    auto compute_chunk = [&](int c, float4 (&qv)[CH], float4 (&bv)[4]) {
        #pragma unroll
        for (int i = 0; i < CH; ++i) {
            float4 q = qv[i];
            const int g = i & 3;
            const float4 f4 = bv[i >> 2];
            float qb = (g == 0) ? f4.x : (g == 1) ? f4.y
                     : (g == 2) ? f4.z : f4.w;
            if (i == 0) { q.x *= sfP; q.y *= sfP; q.z *= sfP; q.w *= sfP; qb *= sfP; }
            if (i == 8) { q.x *= sfM; q.y *= sfM; q.z *= sfM; q.w *= sfM; qb *= sfM; }
            const int t = 1 + c * CH + i;
            if (t < tend) {                    // wave-uniform scalar branch
                // boundary first; pm1 for next step via DPP (VALU pipe)
                const float n7 = fmaf(kf3, p5, p7 + p6) * q.w;
                const float n8 = (p8 + p7) * qb;       // state 8l+8 (512@63)
                const float pm1n = dpp_wave_shr1(n7);  // lane0 -> 0
                const float n0 = (p0 + pm1) * qb;
                const float n1 = fmaf(kf0, pm1, p1 + p0) * q.x;
                const float n2 = (p2 + p1) * qb;
                const float n3 = fmaf(kf1, p1, p3 + p2) * q.y;
                const float n4 = (p4 + p3) * qb;
                const float n5 = fmaf(kf2, p3, p5 + p4) * q.z;
                const float n6 = (p6 + p5) * qb;
                p0 = n0; p1 = n1; p2 = n2; p3 = n3; p4 = n4;
                p5 = n5; p6 = n6; p7 = n7; p8 = n8; pm1 = pm1n;
            }
            if (i == 4)  sfM = snap();         // applied at i==8
            if (i == 12) sfP = snap();         // applied at next chunk i==0
        }
    };

    for (int c = 0; c < NCHUNK; c += 2) {
        compute_chunk(c, qa, bbA);             // uses qa; qbf in flight
        if (c + 2 < NCHUNK) {                  // refill qa <- chunk c+2
            #pragma unroll
            for (int i = 0; i < CH; ++i) {
                int t = 1 + (c + 2) * CH + i; if (t > T_ - 1) t = T_ - 1;
                qa[i] = *qaddr(t);
            }
            #pragma unroll
            for (int j = 0; j < 4; ++j)
                bbA[j] = *(const float4*)&blk[(c + 2) * CH + 4 * j];
        }
        compute_chunk(c + 1, qbf, bbB);        // uses qbf; qa in flight
        if (c + 3 < NCHUNK) {                  // refill qbf <- chunk c+3
            #pragma unroll
            for (int i = 0; i < CH; ++i) {
                int t = 1 + (c + 3) * CH + i; if (t > T_ - 1) t = T_ - 1;
                qbf[i] = *qaddr(t);
            }
            #pragma unroll
            for (int j = 0; j < 4; ++j)
                bbB[j] = *(const float4*)&blk[(c + 3) * CH + 4 * j];
        }
    }
    // apply the last pending scale (its Esc contribution is counted)
    p0 *= sfP; p1 *= sfP; p2 *= sfP; p3 *= sfP; p4 *= sfP;
    p5 *= sfP; p6 *= sfP; p7 *= sfP; p8 *= sfP;

    // epilogue via shuffles only (once — latency irrelevant)
    const int sl = 2 * ll;                     // uniform
    auto pick = [&](int s) -> float {          // s uniform, 1..512
        if (s == 512) return __shfl(p8, 63);
        const int r = s & 7;
        float v = p0;
        v = (r == 1) ? p1 : v; v = (r == 2) ? p2 : v;
        v = (r == 3) ? p3 : v; v = (r == 4) ? p4 : v;
        v = (r == 5) ? p5 : v; v = (r == 6) ? p6 : v;
        v = (r == 7) ? p7 : v;
        return __shfl(v, s >> 3);
    };
    const float la = pick(sl);
    const float lb = pick(sl - 1);
    if (lane == 0) {
        const float tot = la + lb;
        float loss = (float)Esc * LN2F - __logf(tot);
        if (!(loss <= 1e29f)) loss = 0.f;      // zero_infinity
        atomicAdd(out, loss);
    }
}

extern "C" void kernel_launch(void* const* d_in, const int* in_sizes, int n_in,
                              void* d_out, int out_size, void* d_ws, size_t ws_size,
                              hipStream_t stream) {
    float*       lp     = (float*)d_in[0];
    const int*   labels = (const int*)d_in[1];
    const int*   il     = (const int*)d_in[2];
    const int*   ll     = (const int*)d_in[3];
    float* out    = (float*)d_out;
    float* blanks = (float*)d_ws;              // B*T floats = 128 KB

    // workspace layout: [blanks: B*T floats][Q': B*T*256 floats = 32 MB]
    const size_t need = (size_t)B_ * T_ * sizeof(float)
                      + (size_t)B_ * T_ * 256 * sizeof(float);
    const bool use_ws = ws_size >= need;
    float* qdst = use_ws ? (blanks + (size_t)B_ * T_) : lp;
    const int qstride = use_ws ? 256 : V_;     // compact rows in ws mode

    hipMemsetAsync(out, 0, sizeof(float), stream);   // d_out re-poisoned each replay
    ctc_gather<<<dim3(B_ * T_ / 4), dim3(256), 0, stream>>>(
        lp, qdst, qstride, labels, blanks);
    ctc_dp<<<dim3(B_), dim3(64), 0, stream>>>(
        qdst, qstride, blanks, labels, il, ll, out);
}

// Round 4
// 299.522 us; speedup vs baseline: 1.1270x; 1.1270x over previous
//
#include <hip/hip_runtime.h>

// CTC forward loss (sum, zero_infinity), B=32, T=1024, V=1024, L=256, S=513.
//
// Pass 1 (ctc_gather): per (b,t) row — coalesced row copy into LDS via
//   global_load_lds, then the 257 needed probs gathered from LDS.
//   Compacted output to WORKSPACE (stride 256) when ws_size permits ->
//   lp read-only. Fallback: in-place (stride 1024).
//
// Pass 2 (ctc_dp): R13 — single wave per batch item, global_load_lds
//   direct-to-LDS ring (NBUF=4), counted inline-asm vmcnt. Why:
//   R10 post-mortem: producer wave's RELEASE store forces vmcnt(0) ->
//     pipeline depth 0 (250 cyc/step).
//   R12 post-mortem: register double-buffer needs 128 live VGPRs; compiler
//     allocated 104 -> it sank/rematerialized the loads (342 cyc/step,
//     ~4900 cyc exposed latency/chunk). Source-level register pipelines
//     are defeated by the scheduler.
//   global_load_lds has NO VGPR destination (nothing to sink) and a single
//   wave needs NO handshake — just counted s_waitcnt vmcnt(N):
//     prologue: issue blanks + chunks 0..2, vmcnt(32)  (chunk0 landed)
//     iter c:   issue chunk c+3, vmcnt(32)             (chunk c+1 landed;
//               chunk c confirmed last iter -> ~2-chunk lead > HBM latency)
//     tail:     vmcnt(16) at c=61, vmcnt(0) at c=62.
//   Numerics bit-identical to R9-R12 (pass, absmax 1024).

constexpr int B_ = 32, T_ = 1024, V_ = 1024, L_ = 256;
constexpr int CH = 16;           // steps per chunk
constexpr int NCHUNK = 64;       // 64*16 covers t = 1..1024 (t>=tend guarded)
constexpr int NBUF = 4;          // LDS ring depth (64 KB)
constexpr float LN2F = 0.6931471805599453f;

typedef const __attribute__((address_space(1))) unsigned int* gp_t;
typedef __attribute__((address_space(3))) unsigned int* lp_t;

template <int CTRL>
__device__ __forceinline__ float dpp_fmax(float x) {
    // old=0, row_mask=bank_mask=0xf, bound_ctrl=1 (invalid src -> 0);
    // states are nonnegative so fmax with 0 is identity.
    const int t = __builtin_amdgcn_update_dpp(0, __float_as_int(x), CTRL, 0xf, 0xf, true);
    return fmaxf(x, __int_as_float(t));
}

__device__ __forceinline__ float wave_max_dpp(float x) {
    x = dpp_fmax<0x111>(x);   // row_shr:1
    x = dpp_fmax<0x112>(x);   // row_shr:2
    x = dpp_fmax<0x114>(x);   // row_shr:4
    x = dpp_fmax<0x118>(x);   // row_shr:8   (lane 15,31,47,63 = row max)
    x = dpp_fmax<0x142>(x);   // row_bcast:15
    x = dpp_fmax<0x143>(x);   // row_bcast:31 (lane 63 = wave max)
    return __int_as_float(__builtin_amdgcn_readlane(__float_as_int(x), 63));
}

__device__ __forceinline__ float dpp_wave_shr1(float x) {
    // lane i <- lane i-1 across the whole wave; lane 0 -> 0 (bound_ctrl)
    return __int_as_float(
        __builtin_amdgcn_update_dpp(0, __float_as_int(x), 0x138, 0xf, 0xf, true));
}

__global__ __launch_bounds__(256, 8) void ctc_gather(
    const float* __restrict__ lp, float* __restrict__ qdst, int qstride,
    const int* __restrict__ labels, float* __restrict__ blanks)
{
    __shared__ float srow[4][V_];              // 16 KB: one row per wave
    const int wave = threadIdx.x >> 6;
    const int lane = threadIdx.x & 63;
    const int r = blockIdx.x * 4 + wave;       // row in [0, B*T)
    const int b = r >> 10;                     // T = 1024
    const float* row = lp + (size_t)r * V_;
    float* orow = qdst + (size_t)r * qstride;
    const int* labb = labels + b * L_;

    // coalesced row -> LDS (1 KB per instruction); wave-private region,
    // so no barrier is needed anywhere in this kernel.
    #pragma unroll
    for (int j = 0; j < 4; ++j)
        __builtin_amdgcn_global_load_lds((gp_t)(row + 256 * j + 4 * lane),
                                         (lp_t)&srow[wave][256 * j], 16, 0, 0);
    const int4 e = *(const int4*)(labb + 4 * lane);
    asm volatile("s_waitcnt vmcnt(0)" ::: "memory");  // row fully in LDS
                                                      // (also WAR-safe for
                                                      // the in-place path)
    __builtin_amdgcn_sched_barrier(0);
    const float v0 = srow[wave][e.x];
    const float v1 = srow[wave][e.y];
    const float v2 = srow[wave][e.z];
    const float v3 = srow[wave][e.w];
    const float vb = srow[wave][0];
    float4 q;
    q.x = __expf(v0); q.y = __expf(v1); q.z = __expf(v2); q.w = __expf(v3);
    const float qb = __expf(vb);
    *(float4*)(orow + 4 * lane) = q;           // cols 4l..4l+3 (compact)
    if (lane == 0) {
        const int t = r & (T_ - 1);
        blanks[(r & ~(T_ - 1)) + ((t + T_ - 1) & (T_ - 1))] = qb;  // shifted
    }
}

__global__ __launch_bounds__(64, 1) void ctc_dp(
    const float* __restrict__ Q, int qstride,
    const float* __restrict__ blanks, const int* __restrict__ labels,
    const int* __restrict__ input_lens, const int* __restrict__ label_lens,
    float* __restrict__ out)
{
    __shared__ float blk[T_];                  // shifted blank probs (4 KB)
    __shared__ float buf[NBUF][CH][256];       // staged label probs (64 KB)
    const int b    = blockIdx.x;
    const int lane = threadIdx.x & 63;
    const float* Qb  = Q + (size_t)b * T_ * qstride;
    const float* blg = blanks + b * T_;
    const int*  labb = labels + b * L_;
    const int il = input_lens[b];
    const int ll = label_lens[b];
    const int tend = il < T_ ? il : T_;

    auto issue_chunk = [&](int c) {
        #pragma unroll
        for (int i = 0; i < CH; ++i) {
            int t = 1 + c * CH + i; if (t > T_ - 1) t = T_ - 1;
            __builtin_amdgcn_global_load_lds(
                (gp_t)(Qb + (size_t)t * qstride + 4 * lane),
                (lp_t)&buf[c & (NBUF - 1)][i][0], 16, 0, 0);
        }
    };

    // prologue: blanks (4 DMA ops) + chunks 0..2 (48 ops)
    #pragma unroll
    for (int i = 0; i < 4; ++i)
        __builtin_amdgcn_global_load_lds((gp_t)(blg + 256 * i + 4 * lane),
                                         (lp_t)&blk[256 * i], 16, 0, 0);
    issue_chunk(0); issue_chunk(1); issue_chunk(2);

    const int4 e  = *(const int4*)(labb + 4 * lane);
    const int  ep = (lane > 0) ? labb[4 * lane - 1] : -1;
    const float kf0 = ((8 * lane + 1) >= 3 && e.x != ep) ? 1.f : 0.f;
    const float kf1 = (e.y != e.x) ? 1.f : 0.f;
    const float kf2 = (e.z != e.y) ? 1.f : 0.f;
    const float kf3 = (e.w != e.z) ? 1.f : 0.f;
    const float bl0 = blg[T_ - 1];             // blank(t=0), shifted slot
    const float q00 = Qb[0];                   // label-state-1 prob at t=0
    float p0 = (lane == 0) ? bl0 : 0.f;
    float p1 = (lane == 0) ? q00 : 0.f;
    float p2 = 0.f, p3 = 0.f, p4 = 0.f, p5 = 0.f,
          p6 = 0.f, p7 = 0.f, p8 = 0.f;
    int Esc = 0;        // true alpha = stored * 2^{-Esc}
    float pm1 = 0.f;    // alpha[8l-1] entering next step
    float sfP = 1.f, sfM = 1.f;                // pending deferred scales

    // blanks + chunk0 landed (chunks 1,2 = 32 ops still in flight)
    asm volatile("s_waitcnt vmcnt(32)" ::: "memory");
    __builtin_amdgcn_sched_barrier(0);

    // Wave-max via DPP (VALU pipe), exact pow2 factor -> max ~= 2^64.
    auto snap = [&]() -> float {
        float m = fmaxf(fmaxf(fmaxf(fmaxf(p0, p1), fmaxf(p2, p3)),
                              fmaxf(fmaxf(p4, p5), fmaxf(p6, p7))), p8);
        m = wave_max_dpp(m);
        const unsigned eb = (__float_as_uint(m) >> 23) & 0xffu;
        if (eb >= 1u && eb <= 254u) {
            unsigned k = 318u - eb;            // biased exp of 2^(64-(eb-127))
            if (k > 254u) k = 254u;            // clamp (max sf = 2^127)
            Esc += (int)k - 127;
            return __uint_as_float(k << 23);   // exact 2^(k-127)
        }
        return 1.f;
    };

    for (int c = 0; c < NCHUNK; ++c) {
        // ---- pipeline control: issue 3 ahead, counted waits only ----
        if (c + 3 < NCHUNK) {
            issue_chunk(c + 3);                // outstanding {c+1,c+2,c+3}=48
            asm volatile("s_waitcnt vmcnt(32)" ::: "memory");  // c+1 landed
        } else if (c == NCHUNK - 3) {
            asm volatile("s_waitcnt vmcnt(16)" ::: "memory");  // c+1 landed
        } else if (c == NCHUNK - 2) {
            asm volatile("s_waitcnt vmcnt(0)"  ::: "memory");  // all landed
        }
        __builtin_amdgcn_sched_barrier(0);

        // ---- consume chunk c from LDS (landed last iteration) ----
        const float* base = &buf[c & (NBUF - 1)][0][0] + 4 * lane;
        float4 qv[CH];
        #pragma unroll
        for (int i = 0; i < CH; ++i)
            qv[i] = *(const float4*)(base + 256 * i);
        float bb[CH];
        #pragma unroll
        for (int i = 0; i < CH; i += 4) {
            const float4 t4 = *(const float4*)&blk[c * CH + i];
            bb[i] = t4.x; bb[i + 1] = t4.y;
            bb[i + 2] = t4.z; bb[i + 3] = t4.w;
        }
        #pragma unroll
        for (int i = 0; i < CH; ++i) {
            float4 q = qv[i];
            float qb = bb[i];
            if (i == 0) { q.x *= sfP; q.y *= sfP; q.z *= sfP; q.w *= sfP; qb *= sfP; }
            if (i == 8) { q.x *= sfM; q.y *= sfM; q.z *= sfM; q.w *= sfM; qb *= sfM; }
            const int t = 1 + c * CH + i;
            if (t < tend) {                    // wave-uniform scalar branch
                // boundary first; pm1 for next step via DPP (VALU pipe)
                const float n7 = fmaf(kf3, p5, p7 + p6) * q.w;
                const float n8 = (p8 + p7) * qb;       // state 8l+8 (512@63)
                const float pm1n = dpp_wave_shr1(n7);  // lane0 -> 0
                const float n0 = (p0 + pm1) * qb;
                const float n1 = fmaf(kf0, pm1, p1 + p0) * q.x;
                const float n2 = (p2 + p1) * qb;
                const float n3 = fmaf(kf1, p1, p3 + p2) * q.y;
                const float n4 = (p4 + p3) * qb;
                const float n5 = fmaf(kf2, p3, p5 + p4) * q.z;
                const float n6 = (p6 + p5) * qb;
                p0 = n0; p1 = n1; p2 = n2; p3 = n3; p4 = n4;
                p5 = n5; p6 = n6; p7 = n7; p8 = n8; pm1 = pm1n;
            }
            if (i == 4)  sfM = snap();         // applied at i==8
            if (i == 12) sfP = snap();         // applied at next chunk i==0
        }
    }
    // apply the last pending scale (its Esc contribution is counted)
    p0 *= sfP; p1 *= sfP; p2 *= sfP; p3 *= sfP; p4 *= sfP;
    p5 *= sfP; p6 *= sfP; p7 *= sfP; p8 *= sfP;

    // epilogue via shuffles only (once — latency irrelevant)
    const int sl = 2 * ll;                     // uniform
    auto pick = [&](int s) -> float {          // s uniform, 1..512
        if (s == 512) return __shfl(p8, 63);
        const int r = s & 7;
        float v = p0;
        v = (r == 1) ? p1 : v; v = (r == 2) ? p2 : v;
        v = (r == 3) ? p3 : v; v = (r == 4) ? p4 : v;
        v = (r == 5) ? p5 : v; v = (r == 6) ? p6 : v;
        v = (r == 7) ? p7 : v;
        return __shfl(v, s >> 3);
    };
    const float la = pick(sl);
    const float lb = pick(sl - 1);
    if (lane == 0) {
        const float tot = la + lb;
        float loss = (float)Esc * LN2F - __logf(tot);
        if (!(loss <= 1e29f)) loss = 0.f;      // zero_infinity
        atomicAdd(out, loss);
    }
}

extern "C" void kernel_launch(void* const* d_in, const int* in_sizes, int n_in,
                              void* d_out, int out_size, void* d_ws, size_t ws_size,
                              hipStream_t stream) {
    float*       lp     = (float*)d_in[0];
    const int*   labels = (const int*)d_in[1];
    const int*   il     = (const int*)d_in[2];
    const int*   ll     = (const int*)d_in[3];
    float* out    = (float*)d_out;
    float* blanks = (float*)d_ws;              // B*T floats = 128 KB

    // workspace layout: [blanks: B*T floats][Q': B*T*256 floats = 32 MB]
    const size_t need = (size_t)B_ * T_ * sizeof(float)
                      + (size_t)B_ * T_ * 256 * sizeof(float);
    const bool use_ws = ws_size >= need;
    float* qdst = use_ws ? (blanks + (size_t)B_ * T_) : lp;
    const int qstride = use_ws ? 256 : V_;     // compact rows in ws mode

    hipMemsetAsync(out, 0, sizeof(float), stream);   // d_out re-poisoned each replay
    ctc_gather<<<dim3(B_ * T_ / 4), dim3(256), 0, stream>>>(
        lp, qdst, qstride, labels, blanks);
    ctc_dp<<<dim3(B_), dim3(64), 0, stream>>>(
        qdst, qstride, blanks, labels, il, ll, out);
}